// Round 6
// baseline (156.137 us; speedup 1.0000x reference)
//
#include <hip/hip_runtime.h>

#define N 8192
#define THREADS 256
#define ROWS 8
#define CBLK 1024               // 1024 * 8 = 8192 rows
#define KBLK 1024

// ws float layout (no zeroing needed; every slot is written before finalize)
#define WS_CP 0                        // [0 .. 5*CBLK)   cox partials [5][CBLK]
#define WS_KP (5 * CBLK)               // [.. + 2*KBLK)   kl partials  [2][KBLK]

__device__ __forceinline__ float waveSum(float v) {
#pragma unroll
    for (int off = 32; off > 0; off >>= 1) v += __shfl_down(v, off, 64);
    return v;
}

__device__ __forceinline__ float4 exp4(float4 h) {
    return make_float4(__expf(h.x), __expf(h.y), __expf(h.z), __expf(h.w));
}

__device__ __forceinline__ float kl4(float4 l, float4 s) {
    float k;
    k  = 0.5f * (s.x * s.x + l.x * l.x) - __logf(s.x) - 0.5f;
    k += 0.5f * (s.y * s.y + l.y * l.y) - __logf(s.y) - 0.5f;
    k += 0.5f * (s.z * s.z + l.z * l.z) - __logf(s.z) - 0.5f;
    k += 0.5f * (s.w * s.w + l.w * l.w) - __logf(s.w) - 0.5f;
    return k;
}

// ---------------- Cox: 1024 blocks x 8 rows, prefetch-1 pipeline ----------------
// (256,4): 128-VGPR cap, 4 blocks/CU co-resident. Prefetch regs ~28 + acc 40
// must fit; R5 evidence: this code shape allocates ~96 VGPR.
__global__ __launch_bounds__(THREADS, 4) void cox_kernel(
    const float* __restrict__ jlh, const float* __restrict__ mlh,
    const float* __restrict__ target, float* __restrict__ ws)
{
    const int tid  = threadIdx.x;
    const int lane = tid & 63, wid = tid >> 6;
    const int c  = blockIdx.x;
    const int i0 = c * ROWS;

    const float4* tg4 = (const float4*)target;
    const float4* jl4 = (const float4*)jlh;
    const float4* m04 = (const float4*)mlh;
    const float4* m14 = (const float4*)(mlh + N);
    const float4* m24 = (const float4*)(mlh + 2 * N);
    const float4* m34 = (const float4*)(mlh + 3 * N);

    float t_i[ROWS];
#pragma unroll
    for (int r = 0; r < ROWS; ++r) t_i[r] = target[2 * (i0 + r)];

    float acc[ROWS][5];
#pragma unroll
    for (int r = 0; r < ROWS; ++r)
#pragma unroll
        for (int s = 0; s < 5; ++s) acc[r][s] = 0.f;

    // software pipeline: prefetch iteration g+1 while computing g
    int q = tid;
    float4 p_t1 = tg4[2 * q], p_t2 = tg4[2 * q + 1];
    float4 p_j  = jl4[q];
    float4 p_m0 = m04[q], p_m1 = m14[q], p_m2 = m24[q], p_m3 = m34[q];

#pragma unroll
    for (int g = 0; g < N / (THREADS * 4); ++g) {   // 8 iterations
        const float4 tj = make_float4(p_t1.x, p_t1.z, p_t2.x, p_t2.z);
        const float4 x0 = exp4(p_j);
        const float4 x1 = exp4(p_m0);
        const float4 x2 = exp4(p_m1);
        const float4 x3 = exp4(p_m2);
        const float4 x4 = exp4(p_m3);
        if (g < N / (THREADS * 4) - 1) {
            q += THREADS;
            p_t1 = tg4[2 * q]; p_t2 = tg4[2 * q + 1];
            p_j  = jl4[q];
            p_m0 = m04[q]; p_m1 = m14[q]; p_m2 = m24[q]; p_m3 = m34[q];
        }
#pragma unroll
        for (int r = 0; r < ROWS; ++r) {
            const float ti = t_i[r];
            const float m0 = (tj.x >= ti) ? 1.f : 0.f;
            const float m1 = (tj.y >= ti) ? 1.f : 0.f;
            const float m2 = (tj.z >= ti) ? 1.f : 0.f;
            const float m3 = (tj.w >= ti) ? 1.f : 0.f;
            acc[r][0] = fmaf(m0, x0.x, fmaf(m1, x0.y, fmaf(m2, x0.z, fmaf(m3, x0.w, acc[r][0]))));
            acc[r][1] = fmaf(m0, x1.x, fmaf(m1, x1.y, fmaf(m2, x1.z, fmaf(m3, x1.w, acc[r][1]))));
            acc[r][2] = fmaf(m0, x2.x, fmaf(m1, x2.y, fmaf(m2, x2.z, fmaf(m3, x2.w, acc[r][2]))));
            acc[r][3] = fmaf(m0, x3.x, fmaf(m1, x3.y, fmaf(m2, x3.z, fmaf(m3, x3.w, acc[r][3]))));
            acc[r][4] = fmaf(m0, x4.x, fmaf(m1, x4.y, fmaf(m2, x4.z, fmaf(m3, x4.w, acc[r][4]))));
        }
    }

#pragma unroll
    for (int r = 0; r < ROWS; ++r)
#pragma unroll
        for (int s = 0; s < 5; ++s) acc[r][s] = waveSum(acc[r][s]);

    __shared__ float red[4][ROWS][5];
    __shared__ float crs[ROWS][5];
    if (lane == 0) {
#pragma unroll
        for (int r = 0; r < ROWS; ++r)
#pragma unroll
            for (int s = 0; s < 5; ++s) red[wid][r][s] = acc[r][s];
    }
    __syncthreads();

    if (tid < ROWS * 5) {
        const int r = tid / 5, s = tid % 5;
        const float risk = red[0][r][s] + red[1][r][s] + red[2][r][s] + red[3][r][s];
        const float ev = target[2 * (i0 + r) + 1];
        const float h = (s == 0) ? jlh[i0 + r] : mlh[(s - 1) * N + i0 + r];
        crs[r][s] = ev * (h - __logf(risk));
    }
    __syncthreads();

    if (tid < 5) {
        float v = 0.f;
#pragma unroll
        for (int r = 0; r < ROWS; ++r) v += crs[r][tid];
        ws[WS_CP + tid * CBLK + c] = v;
    }
}

// ---------------- KL: all 20 loads in flight before compute ----------------
__global__ __launch_bounds__(THREADS) void kl_kernel(
    const float4* __restrict__ jloc4, const float4* __restrict__ jscale4,
    const float4* __restrict__ mloc4, const float4* __restrict__ mscale4,
    float* __restrict__ ws)
{
    const int tid  = threadIdx.x;
    const int lane = tid & 63, wid = tid >> 6;
    const int k = blockIdx.x;

    float4 jl[2], js[2], ml[8], ms[8];
#pragma unroll
    for (int it = 0; it < 2; ++it) {            // joint: 512 f4/block
        const int idx = k * 512 + it * THREADS + tid;
        jl[it] = jloc4[idx]; js[it] = jscale4[idx];
    }
#pragma unroll
    for (int it = 0; it < 8; ++it) {            // modality: 2048 f4/block
        const int idx = k * 2048 + it * THREADS + tid;
        ml[it] = mloc4[idx]; ms[it] = mscale4[idx];
    }

    float kj = 0.f, km = 0.f;
#pragma unroll
    for (int it = 0; it < 2; ++it) kj += kl4(jl[it], js[it]);
#pragma unroll
    for (int it = 0; it < 8; ++it) km += kl4(ml[it], ms[it]);

    kj = waveSum(kj);
    km = waveSum(km);
    __shared__ float kred[2][4];
    if (lane == 0) { kred[0][wid] = kj; kred[1][wid] = km; }
    __syncthreads();
    if (tid == 0)
        ws[WS_KP + k] = kred[0][0] + kred[0][1] + kred[0][2] + kred[0][3];
    if (tid == 1)
        ws[WS_KP + KBLK + k] = kred[1][0] + kred[1][1] + kred[1][2] + kred[1][3];
}

__global__ __launch_bounds__(THREADS) void finalize_kernel(
    const float* __restrict__ target, const float* __restrict__ ws,
    const float* __restrict__ alpha_p, const float* __restrict__ beta_p,
    float* __restrict__ out)
{
    const int tid = threadIdx.x;
    float ev = 0.f;
    for (int i = tid; i < N; i += THREADS) ev += target[2 * i + 1];
    float s0 = 0.f, s1 = 0.f, s2 = 0.f, s3 = 0.f, s4 = 0.f, kj = 0.f, km = 0.f;
    for (int i = tid; i < CBLK; i += THREADS) {
        s0 += ws[WS_CP + 0 * CBLK + i];
        s1 += ws[WS_CP + 1 * CBLK + i];
        s2 += ws[WS_CP + 2 * CBLK + i];
        s3 += ws[WS_CP + 3 * CBLK + i];
        s4 += ws[WS_CP + 4 * CBLK + i];
    }
    for (int i = tid; i < KBLK; i += THREADS) {
        kj += ws[WS_KP + i];
        km += ws[WS_KP + KBLK + i];
    }
    ev = waveSum(ev); s0 = waveSum(s0); s1 = waveSum(s1); s2 = waveSum(s2);
    s3 = waveSum(s3); s4 = waveSum(s4); kj = waveSum(kj); km = waveSum(km);

    __shared__ float red[8][4];
    const int lane = tid & 63, wid = tid >> 6;
    if (lane == 0) {
        red[0][wid] = ev; red[1][wid] = s0; red[2][wid] = s1; red[3][wid] = s2;
        red[4][wid] = s3; red[5][wid] = s4; red[6][wid] = kj; red[7][wid] = km;
    }
    __syncthreads();
    if (tid == 0) {
        float v[8];
#pragma unroll
        for (int q = 0; q < 8; ++q) v[q] = red[q][0] + red[q][1] + red[q][2] + red[q][3];
        const float EV = v[0];
        const float alpha = alpha_p[0], beta = beta_p[0];
        const float cox_j = -v[1] / EV;
        const float cox_m = -(v[2] + v[3] + v[4] + v[5]) / EV;
        out[0] = cox_j + beta * (v[6] / (float)N) + alpha * (cox_m + beta * (v[7] / (float)N));
    }
}

extern "C" void kernel_launch(void* const* d_in, const int* in_sizes, int n_in,
                              void* d_out, int out_size, void* d_ws, size_t ws_size,
                              hipStream_t stream) {
    const float* jlh    = (const float*)d_in[0];  // (N,)
    const float* mlh    = (const float*)d_in[1];  // (M,N)
    const float* jloc   = (const float*)d_in[2];  // (N,L)
    const float* jscale = (const float*)d_in[3];  // (N,L)
    const float* mloc   = (const float*)d_in[4];  // (M,N,L)
    const float* mscale = (const float*)d_in[5];  // (M,N,L)
    const float* target = (const float*)d_in[6];  // (N,2)
    const float* alpha  = (const float*)d_in[7];
    const float* beta   = (const float*)d_in[8];
    float* out = (float*)d_out;
    float* ws  = (float*)d_ws;

    kl_kernel<<<KBLK, THREADS, 0, stream>>>(
        (const float4*)jloc, (const float4*)jscale,
        (const float4*)mloc, (const float4*)mscale, ws);

    cox_kernel<<<CBLK, THREADS, 0, stream>>>(jlh, mlh, target, ws);

    finalize_kernel<<<1, THREADS, 0, stream>>>(target, ws, alpha, beta, out);
}

// Round 7
// 147.736 us; speedup vs baseline: 1.0569x; 1.0569x over previous
//
#include <hip/hip_runtime.h>

#define N 8192
#define THREADS 256
#define ROWS 16
#define CBLK 512                // 512 * 16 = 8192 rows, exactly 2 blocks/CU, one round
#define KLBLK 1024

#define NJ4 (N * 256 / 4)       // joint f4-pairs  = 524288
#define NM4 (4 * N * 256 / 4)   // modality f4-pairs = 2097152

// ws float layout (no zeroing needed; every slot is written before finalize)
#define WS_CP 0                        // [0 .. 5*CBLK)   cox partials [5][CBLK]
#define WS_KP (5 * CBLK)               // [.. + 2*KLBLK)  kl partials  [2][KLBLK]

__device__ __forceinline__ float waveSum(float v) {
#pragma unroll
    for (int off = 32; off > 0; off >>= 1) v += __shfl_down(v, off, 64);
    return v;
}

__device__ __forceinline__ float4 exp4(float4 h) {
    return make_float4(__expf(h.x), __expf(h.y), __expf(h.z), __expf(h.w));
}

__device__ __forceinline__ float kl4(float4 l, float4 s) {
    float k;
    k  = 0.5f * (s.x * s.x + l.x * l.x) - __logf(s.x) - 0.5f;
    k += 0.5f * (s.y * s.y + l.y * l.y) - __logf(s.y) - 0.5f;
    k += 0.5f * (s.z * s.z + l.z * l.z) - __logf(s.z) - 0.5f;
    k += 0.5f * (s.w * s.w + l.w * l.w) - __logf(s.w) - 0.5f;
    return k;
}

// ---------------- KL: streaming, occupancy-first ----------------
// (256,8): 64-VGPR cap -> 8 waves/SIMD. KL is HBM-bound (84 MB ~= 13 us);
// latency hiding here comes from wave count (TLP), not per-thread batching.
// R6's 20-loads-upfront variant wanted ~80 data VGPRs and starved occupancy.
__global__ __launch_bounds__(THREADS, 8) void kl_kernel(
    const float4* __restrict__ jloc4, const float4* __restrict__ jscale4,
    const float4* __restrict__ mloc4, const float4* __restrict__ mscale4,
    float* __restrict__ ws)
{
    const int tid  = threadIdx.x;
    const int lane = tid & 63, wid = tid >> 6;
    const int gt   = blockIdx.x * THREADS + tid;
    const int nth  = KLBLK * THREADS;           // 262144

    float kj = 0.f, km = 0.f;
#pragma unroll
    for (int it = 0; it < NJ4 / (KLBLK * THREADS); ++it) {   // 2 iters
        const int idx = it * nth + gt;
        kj += kl4(jloc4[idx], jscale4[idx]);
    }
#pragma unroll
    for (int it = 0; it < NM4 / (KLBLK * THREADS); ++it) {   // 8 iters, unrolled -> loads overlap
        const int idx = it * nth + gt;
        km += kl4(mloc4[idx], mscale4[idx]);
    }

    kj = waveSum(kj);
    km = waveSum(km);
    __shared__ float kred[2][4];
    if (lane == 0) { kred[0][wid] = kj; kred[1][wid] = km; }
    __syncthreads();
    if (tid == 0)
        ws[WS_KP + blockIdx.x] = kred[0][0] + kred[0][1] + kred[0][2] + kred[0][3];
    if (tid == 1)
        ws[WS_KP + KLBLK + blockIdx.x] = kred[1][0] + kred[1][1] + kred[1][2] + kred[1][3];
}

// ---------------- Cox: 512 blocks x 16 rows, prefetch-1 pipeline ----------------
// (256,2): VALU-bound path; needs ~96+ VGPR for acc[16][5] + prefetch buffer.
// R4/R6 evidence: (256,4) collapses to ~60 VGPR, drops the pipeline, 2-3x slower.
// Do NOT tighten the second argument.
__global__ __launch_bounds__(THREADS, 2) void cox_kernel(
    const float* __restrict__ jlh, const float* __restrict__ mlh,
    const float* __restrict__ target, float* __restrict__ ws)
{
    const int tid  = threadIdx.x;
    const int lane = tid & 63, wid = tid >> 6;
    const int c  = blockIdx.x;
    const int i0 = c * ROWS;

    const float4* tg4 = (const float4*)target;
    const float4* jl4 = (const float4*)jlh;
    const float4* m04 = (const float4*)mlh;
    const float4* m14 = (const float4*)(mlh + N);
    const float4* m24 = (const float4*)(mlh + 2 * N);
    const float4* m34 = (const float4*)(mlh + 3 * N);

    float t_i[ROWS];
#pragma unroll
    for (int r = 0; r < ROWS; ++r) t_i[r] = target[2 * (i0 + r)];

    float acc[ROWS][5];
#pragma unroll
    for (int r = 0; r < ROWS; ++r)
#pragma unroll
        for (int s = 0; s < 5; ++s) acc[r][s] = 0.f;

    // software pipeline: prefetch iteration g+1 while computing g
    int q = tid;
    float4 p_t1 = tg4[2 * q], p_t2 = tg4[2 * q + 1];
    float4 p_j  = jl4[q];
    float4 p_m0 = m04[q], p_m1 = m14[q], p_m2 = m24[q], p_m3 = m34[q];

#pragma unroll
    for (int g = 0; g < N / (THREADS * 4); ++g) {   // 8 iterations
        const float4 tj = make_float4(p_t1.x, p_t1.z, p_t2.x, p_t2.z);
        const float4 x0 = exp4(p_j);
        const float4 x1 = exp4(p_m0);
        const float4 x2 = exp4(p_m1);
        const float4 x3 = exp4(p_m2);
        const float4 x4 = exp4(p_m3);
        if (g < N / (THREADS * 4) - 1) {
            q += THREADS;
            p_t1 = tg4[2 * q]; p_t2 = tg4[2 * q + 1];
            p_j  = jl4[q];
            p_m0 = m04[q]; p_m1 = m14[q]; p_m2 = m24[q]; p_m3 = m34[q];
        }
#pragma unroll
        for (int r = 0; r < ROWS; ++r) {
            const float ti = t_i[r];
            const float m0 = (tj.x >= ti) ? 1.f : 0.f;
            const float m1 = (tj.y >= ti) ? 1.f : 0.f;
            const float m2 = (tj.z >= ti) ? 1.f : 0.f;
            const float m3 = (tj.w >= ti) ? 1.f : 0.f;
            acc[r][0] = fmaf(m0, x0.x, fmaf(m1, x0.y, fmaf(m2, x0.z, fmaf(m3, x0.w, acc[r][0]))));
            acc[r][1] = fmaf(m0, x1.x, fmaf(m1, x1.y, fmaf(m2, x1.z, fmaf(m3, x1.w, acc[r][1]))));
            acc[r][2] = fmaf(m0, x2.x, fmaf(m1, x2.y, fmaf(m2, x2.z, fmaf(m3, x2.w, acc[r][2]))));
            acc[r][3] = fmaf(m0, x3.x, fmaf(m1, x3.y, fmaf(m2, x3.z, fmaf(m3, x3.w, acc[r][3]))));
            acc[r][4] = fmaf(m0, x4.x, fmaf(m1, x4.y, fmaf(m2, x4.z, fmaf(m3, x4.w, acc[r][4]))));
        }
    }

#pragma unroll
    for (int r = 0; r < ROWS; ++r)
#pragma unroll
        for (int s = 0; s < 5; ++s) acc[r][s] = waveSum(acc[r][s]);

    __shared__ float red[4][ROWS][5];
    __shared__ float crs[ROWS][5];
    if (lane == 0) {
#pragma unroll
        for (int r = 0; r < ROWS; ++r)
#pragma unroll
            for (int s = 0; s < 5; ++s) red[wid][r][s] = acc[r][s];
    }
    __syncthreads();

    if (tid < ROWS * 5) {
        const int r = tid / 5, s = tid % 5;
        const float risk = red[0][r][s] + red[1][r][s] + red[2][r][s] + red[3][r][s];
        const float ev = target[2 * (i0 + r) + 1];
        const float h = (s == 0) ? jlh[i0 + r] : mlh[(s - 1) * N + i0 + r];
        crs[r][s] = ev * (h - __logf(risk));
    }
    __syncthreads();

    if (tid < 5) {
        float v = 0.f;
#pragma unroll
        for (int r = 0; r < ROWS; ++r) v += crs[r][tid];
        ws[WS_CP + tid * CBLK + c] = v;
    }
}

__global__ __launch_bounds__(THREADS) void finalize_kernel(
    const float* __restrict__ target, const float* __restrict__ ws,
    const float* __restrict__ alpha_p, const float* __restrict__ beta_p,
    float* __restrict__ out)
{
    const int tid = threadIdx.x;
    float ev = 0.f;
    for (int i = tid; i < N; i += THREADS) ev += target[2 * i + 1];
    float s0 = 0.f, s1 = 0.f, s2 = 0.f, s3 = 0.f, s4 = 0.f, kj = 0.f, km = 0.f;
    for (int i = tid; i < CBLK; i += THREADS) {
        s0 += ws[WS_CP + 0 * CBLK + i];
        s1 += ws[WS_CP + 1 * CBLK + i];
        s2 += ws[WS_CP + 2 * CBLK + i];
        s3 += ws[WS_CP + 3 * CBLK + i];
        s4 += ws[WS_CP + 4 * CBLK + i];
    }
    for (int i = tid; i < KLBLK; i += THREADS) {
        kj += ws[WS_KP + i];
        km += ws[WS_KP + KLBLK + i];
    }
    ev = waveSum(ev); s0 = waveSum(s0); s1 = waveSum(s1); s2 = waveSum(s2);
    s3 = waveSum(s3); s4 = waveSum(s4); kj = waveSum(kj); km = waveSum(km);

    __shared__ float red[8][4];
    const int lane = tid & 63, wid = tid >> 6;
    if (lane == 0) {
        red[0][wid] = ev; red[1][wid] = s0; red[2][wid] = s1; red[3][wid] = s2;
        red[4][wid] = s3; red[5][wid] = s4; red[6][wid] = kj; red[7][wid] = km;
    }
    __syncthreads();
    if (tid == 0) {
        float v[8];
#pragma unroll
        for (int q = 0; q < 8; ++q) v[q] = red[q][0] + red[q][1] + red[q][2] + red[q][3];
        const float EV = v[0];
        const float alpha = alpha_p[0], beta = beta_p[0];
        const float cox_j = -v[1] / EV;
        const float cox_m = -(v[2] + v[3] + v[4] + v[5]) / EV;
        out[0] = cox_j + beta * (v[6] / (float)N) + alpha * (cox_m + beta * (v[7] / (float)N));
    }
}

extern "C" void kernel_launch(void* const* d_in, const int* in_sizes, int n_in,
                              void* d_out, int out_size, void* d_ws, size_t ws_size,
                              hipStream_t stream) {
    const float* jlh    = (const float*)d_in[0];  // (N,)
    const float* mlh    = (const float*)d_in[1];  // (M,N)
    const float* jloc   = (const float*)d_in[2];  // (N,L)
    const float* jscale = (const float*)d_in[3];  // (N,L)
    const float* mloc   = (const float*)d_in[4];  // (M,N,L)
    const float* mscale = (const float*)d_in[5];  // (M,N,L)
    const float* target = (const float*)d_in[6];  // (N,2)
    const float* alpha  = (const float*)d_in[7];
    const float* beta   = (const float*)d_in[8];
    float* out = (float*)d_out;
    float* ws  = (float*)d_ws;

    kl_kernel<<<KLBLK, THREADS, 0, stream>>>(
        (const float4*)jloc, (const float4*)jscale,
        (const float4*)mloc, (const float4*)mscale, ws);

    cox_kernel<<<CBLK, THREADS, 0, stream>>>(jlh, mlh, target, ws);

    finalize_kernel<<<1, THREADS, 0, stream>>>(target, ws, alpha, beta, out);
}